// Round 1
// baseline (407.075 us; speedup 1.0000x reference)
//
#include <hip/hip_runtime.h>

#define HOP 512
#define NBINS 84
#define TT 8
#define BLOCK 256

// per-bin effective kernel length (nonzero prefix), with safety margin.
// Elements beyond the true ceil() are zeros in the kernel rows (hann endpoints
// are 0 and rows are zero-padded), so a small over-estimate is exact.
__device__ __forceinline__ int bin_len(int k, int max_win) {
    double Q = 1.0 / (exp2(1.0 / 12.0) - 1.0);
    double freq = 32.7 * exp2((double)k / 12.0);
    int len = (int)ceil(Q * 22050.0 / freq) + 8;
    return len > max_win ? max_win : len;
}

// Repack kr/ki into ws with padded stride (16B-aligned rows, zero pad).
__global__ void cqt_repack(const float* __restrict__ kr, const float* __restrict__ ki,
                           float* __restrict__ dst, int max_win, int pad) {
    int total = 2 * NBINS * pad;
    for (int idx = blockIdx.x * blockDim.x + threadIdx.x; idx < total;
         idx += gridDim.x * blockDim.x) {
        int c = idx % pad;
        int row = idx / pad;  // 0..167
        int k = (row < NBINS) ? row : row - NBINS;
        const float* src = (row < NBINS) ? kr : ki;
        dst[idx] = (c < max_win) ? src[(size_t)k * max_win + c] : 0.0f;
    }
}

template <bool ALIGNED>
__global__ __launch_bounds__(BLOCK) void cqt_main(
    const float* __restrict__ audio,
    const float* __restrict__ krp, const float* __restrict__ kip,
    float* __restrict__ out,
    int T, int nb, int max_win, int kstride, int ngt, int span) {
    extern __shared__ float a_lds[];

    int b = blockIdx.x / ngt;
    int tg = blockIdx.x % ngt;
    int t0 = tg * TT;
    const float* ab = audio + (size_t)b * T;
    int g0 = t0 * HOP;

    // stage audio window (zero-padded beyond T) into LDS
    for (int i = (int)threadIdx.x * 4; i < span; i += BLOCK * 4) {
        int g = g0 + i;
        float4 v;
        if (g + 3 < T) {
            v = *reinterpret_cast<const float4*>(ab + g);
        } else {
            v.x = (g     < T) ? ab[g]     : 0.0f;
            v.y = (g + 1 < T) ? ab[g + 1] : 0.0f;
            v.z = (g + 2 < T) ? ab[g + 2] : 0.0f;
            v.w = (g + 3 < T) ? ab[g + 3] : 0.0f;
        }
        *reinterpret_cast<float4*>(a_lds + i) = v;
    }
    __syncthreads();

    int wave = threadIdx.x >> 6;
    int lane = threadIdx.x & 63;

    for (int k = wave; k < NBINS; k += BLOCK / 64) {
        int len = bin_len(k, max_win);
        const float* krow = krp + (size_t)k * kstride;
        const float* kirow = kip + (size_t)k * kstride;

        float accR[TT], accI[TT];
#pragma unroll
        for (int t = 0; t < TT; ++t) { accR[t] = 0.0f; accI[t] = 0.0f; }

        for (int n = lane * 4; n < len; n += 64 * 4) {
            float4 r4, i4;
            if (ALIGNED) {
                r4 = *reinterpret_cast<const float4*>(krow + n);
                i4 = *reinterpret_cast<const float4*>(kirow + n);
            } else {
                r4.x = krow[n];
                r4.y = (n + 1 < max_win) ? krow[n + 1] : 0.0f;
                r4.z = (n + 2 < max_win) ? krow[n + 2] : 0.0f;
                r4.w = (n + 3 < max_win) ? krow[n + 3] : 0.0f;
                i4.x = kirow[n];
                i4.y = (n + 1 < max_win) ? kirow[n + 1] : 0.0f;
                i4.z = (n + 2 < max_win) ? kirow[n + 2] : 0.0f;
                i4.w = (n + 3 < max_win) ? kirow[n + 3] : 0.0f;
            }
#pragma unroll
            for (int tb = 0; tb < TT; ++tb) {
                float4 a4 = *reinterpret_cast<const float4*>(a_lds + tb * HOP + n);
                accR[tb] = fmaf(a4.x, r4.x, accR[tb]);
                accR[tb] = fmaf(a4.y, r4.y, accR[tb]);
                accR[tb] = fmaf(a4.z, r4.z, accR[tb]);
                accR[tb] = fmaf(a4.w, r4.w, accR[tb]);
                accI[tb] = fmaf(a4.x, i4.x, accI[tb]);
                accI[tb] = fmaf(a4.y, i4.y, accI[tb]);
                accI[tb] = fmaf(a4.z, i4.z, accI[tb]);
                accI[tb] = fmaf(a4.w, i4.w, accI[tb]);
            }
        }

#pragma unroll
        for (int tb = 0; tb < TT; ++tb) {
            float r = accR[tb], m = accI[tb];
#pragma unroll
            for (int off = 32; off > 0; off >>= 1) {
                r += __shfl_down(r, off);
                m += __shfl_down(m, off);
            }
            if (lane == 0 && (t0 + tb) < nb) {
                float2* o = reinterpret_cast<float2*>(
                    out + (((size_t)b * nb + (t0 + tb)) * NBINS + k) * 2);
                *o = make_float2(r, m);
            }
        }
    }
}

extern "C" void kernel_launch(void* const* d_in, const int* in_sizes, int n_in,
                              void* d_out, int out_size, void* d_ws, size_t ws_size,
                              hipStream_t stream) {
    const float* audio = (const float*)d_in[0];
    const float* kr = (const float*)d_in[1];
    const float* ki = (const float*)d_in[2];
    float* out = (float*)d_out;

    const int T = 661500;                    // from setup_inputs
    const int B = in_sizes[0] / T;           // 4
    const int max_win = in_sizes[1] / NBINS; // 11341
    const int nb = T / HOP + 1;              // 1292

    int span = (TT - 1) * HOP + max_win + 4;
    span = (span + 3) & ~3;
    size_t lds_bytes = (size_t)span * sizeof(float);

    int ngt = (nb + TT - 1) / TT;
    dim3 grid(B * ngt), block(BLOCK);

    int pad = ((max_win + 3) & ~3) + 4;
    size_t need = (size_t)2 * NBINS * pad * sizeof(float);

    if (ws_size >= need) {
        float* wk = (float*)d_ws;
        int total = 2 * NBINS * pad;
        int rblocks = (total + BLOCK - 1) / BLOCK;
        if (rblocks > 2048) rblocks = 2048;
        cqt_repack<<<rblocks, BLOCK, 0, stream>>>(kr, ki, wk, max_win, pad);
        cqt_main<true><<<grid, block, lds_bytes, stream>>>(
            audio, wk, wk + (size_t)NBINS * pad, out, T, nb, max_win, pad, ngt, span);
    } else {
        cqt_main<false><<<grid, block, lds_bytes, stream>>>(
            audio, kr, ki, out, T, nb, max_win, max_win, ngt, span);
    }
}

// Round 2
// 132.407 us; speedup vs baseline: 3.0744x; 3.0744x over previous
//
#include <hip/hip_runtime.h>

#define HOP 512
#define NBINS 84
#define TT 8
#define BLOCK 256
#define KB 4        // bins per group (adjacent -> lengths within 19%)
#define NGROUPS 21  // NBINS / KB
#define CHUNK 256   // floats processed per inner iteration (64 lanes x float4)

// per-bin effective kernel length (nonzero prefix) + safety margin.
// Elements beyond the true ceil() are zeros in the kernel rows, so an
// over-estimate only adds exact zero FMAs.
__device__ __forceinline__ int bin_len(int k, int max_win) {
    double Q = 1.0 / (exp2(1.0 / 12.0) - 1.0);
    double freq = 32.7 * exp2((double)k / 12.0);
    int len = (int)ceil(Q * 22050.0 / freq) + 8;
    return len > max_win ? max_win : len;
}

// Repack kr/ki into ws with stride padded to a CHUNK multiple (zero-filled),
// so the main loop's vector reads never cross into the next row.
__global__ void cqt_repack(const float* __restrict__ kr, const float* __restrict__ ki,
                           float* __restrict__ dst, int max_win, int pad) {
    int total = 2 * NBINS * pad;
    for (int idx = blockIdx.x * blockDim.x + threadIdx.x; idx < total;
         idx += gridDim.x * blockDim.x) {
        int c = idx % pad;
        int row = idx / pad;  // 0..167
        int k = (row < NBINS) ? row : row - NBINS;
        const float* src = (row < NBINS) ? kr : ki;
        dst[idx] = (c < max_win) ? src[(size_t)k * max_win + c] : 0.0f;
    }
}

template <bool ALIGNED>
__global__ __launch_bounds__(BLOCK) void cqt_main(
    const float* __restrict__ audio,
    const float* __restrict__ krp, const float* __restrict__ kip,
    float* __restrict__ out,
    int T, int nb, int max_win, int kstride, int ngt, int span) {
    extern __shared__ float a_lds[];

    int b = blockIdx.x / ngt;
    int tg = blockIdx.x % ngt;
    int t0 = tg * TT;
    const float* ab = audio + (size_t)b * T;
    int g0 = t0 * HOP;

    // stage audio window (zero beyond T) into LDS
    for (int i = (int)threadIdx.x * 4; i < span; i += BLOCK * 4) {
        int g = g0 + i;
        float4 v;
        if (g + 3 < T) {
            v = *reinterpret_cast<const float4*>(ab + g);
        } else {
            v.x = (g     < T) ? ab[g]     : 0.0f;
            v.y = (g + 1 < T) ? ab[g + 1] : 0.0f;
            v.z = (g + 2 < T) ? ab[g + 2] : 0.0f;
            v.w = (g + 3 < T) ? ab[g + 3] : 0.0f;
        }
        *reinterpret_cast<float4*>(a_lds + i) = v;
    }
    __syncthreads();

    int wave = (int)threadIdx.x >> 6;
    int lane = (int)threadIdx.x & 63;

    // Greedy group->wave assignment by chunk count (uniform across threads).
    int l0 = 0, l1 = 0, l2 = 0, l3 = 0;
    for (int g = 0; g < NGROUPS; ++g) {
        int k0 = g * KB;
        int blen = bin_len(k0, max_win);  // longest bin in the group
        int chunks = (blen + CHUNK - 1) / CHUNK;

        int w = 0, lmin = l0;
        if (l1 < lmin) { lmin = l1; w = 1; }
        if (l2 < lmin) { lmin = l2; w = 2; }
        if (l3 < lmin) { lmin = l3; w = 3; }
        if (w == 0) l0 += chunks; else if (w == 1) l1 += chunks;
        else if (w == 2) l2 += chunks; else l3 += chunks;
        if (w != wave) continue;

        // ---- process group [k0, k0+3] ----
        const float* kr0 = krp + (size_t)k0 * kstride;
        const float* ki0 = kip + (size_t)k0 * kstride;

        float acc[64];  // idx = tb*8 + bin*2 + reim
#pragma unroll
        for (int i = 0; i < 64; ++i) acc[i] = 0.0f;

        for (int j = 0; j < chunks; ++j) {
            int n = j * CHUNK + lane * 4;
            float4 kr4[KB], ki4[KB];
#pragma unroll
            for (int i = 0; i < KB; ++i) {
                const float* rr = kr0 + (size_t)i * kstride;
                const float* mm = ki0 + (size_t)i * kstride;
                if (ALIGNED) {
                    kr4[i] = *reinterpret_cast<const float4*>(rr + n);
                    ki4[i] = *reinterpret_cast<const float4*>(mm + n);
                } else {
                    kr4[i].x = (n     < max_win) ? rr[n]     : 0.0f;
                    kr4[i].y = (n + 1 < max_win) ? rr[n + 1] : 0.0f;
                    kr4[i].z = (n + 2 < max_win) ? rr[n + 2] : 0.0f;
                    kr4[i].w = (n + 3 < max_win) ? rr[n + 3] : 0.0f;
                    ki4[i].x = (n     < max_win) ? mm[n]     : 0.0f;
                    ki4[i].y = (n + 1 < max_win) ? mm[n + 1] : 0.0f;
                    ki4[i].z = (n + 2 < max_win) ? mm[n + 2] : 0.0f;
                    ki4[i].w = (n + 3 < max_win) ? mm[n + 3] : 0.0f;
                }
            }
#pragma unroll
            for (int tb = 0; tb < TT; ++tb) {
                float4 a = *reinterpret_cast<const float4*>(a_lds + tb * HOP + n);
#pragma unroll
                for (int i = 0; i < KB; ++i) {
                    float r = acc[tb * 8 + i * 2 + 0];
                    float m = acc[tb * 8 + i * 2 + 1];
                    r = fmaf(a.x, kr4[i].x, r);
                    r = fmaf(a.y, kr4[i].y, r);
                    r = fmaf(a.z, kr4[i].z, r);
                    r = fmaf(a.w, kr4[i].w, r);
                    m = fmaf(a.x, ki4[i].x, m);
                    m = fmaf(a.y, ki4[i].y, m);
                    m = fmaf(a.z, ki4[i].z, m);
                    m = fmaf(a.w, ki4[i].w, m);
                    acc[tb * 8 + i * 2 + 0] = r;
                    acc[tb * 8 + i * 2 + 1] = m;
                }
            }
        }

        // Halving-butterfly reduction of 64 values across 64 lanes.
        // After 6 rounds, lane l holds the full sum of original acc[l].
#pragma unroll
        for (int r = 0; r < 6; ++r) {
            int off = 1 << r;
            int cnt = 32 >> r;
            bool hi = (lane & off) != 0;
#pragma unroll
            for (int i = 0; i < cnt; ++i) {
                float a = acc[2 * i], bb = acc[2 * i + 1];
                float mine = hi ? bb : a;
                float oth  = hi ? a : bb;
                mine += __shfl_xor(oth, off);
                acc[i] = mine;
            }
        }

        // lane l holds value l = tb*8 + bin*2 + reim
        int tb = lane >> 3;
        int bi = (lane >> 1) & 3;
        int rr = lane & 1;
        int t = t0 + tb;
        if (t < nb) {
            out[(((size_t)b * nb + t) * NBINS + (k0 + bi)) * 2 + rr] = acc[0];
        }
    }
}

extern "C" void kernel_launch(void* const* d_in, const int* in_sizes, int n_in,
                              void* d_out, int out_size, void* d_ws, size_t ws_size,
                              hipStream_t stream) {
    const float* audio = (const float*)d_in[0];
    const float* kr = (const float*)d_in[1];
    const float* ki = (const float*)d_in[2];
    float* out = (float*)d_out;

    const int T = 661500;                    // from setup_inputs
    const int B = in_sizes[0] / T;           // 4
    const int max_win = in_sizes[1] / NBINS; // 11341
    const int nb = T / HOP + 1;              // 1292

    // kernel-row stride padded to CHUNK multiple covering max_win+margin
    int kpad = ((max_win + 8 + CHUNK - 1) / CHUNK) * CHUNK;  // 11520
    int span = (TT - 1) * HOP + kpad;                        // 15104 floats
    size_t lds_bytes = (size_t)span * sizeof(float);         // ~60.4 KB

    int ngt = (nb + TT - 1) / TT;  // 162
    dim3 grid(B * ngt), block(BLOCK);

    size_t need = (size_t)2 * NBINS * kpad * sizeof(float);

    if (ws_size >= need) {
        float* wk = (float*)d_ws;
        int total = 2 * NBINS * kpad;
        int rblocks = (total + BLOCK - 1) / BLOCK;
        if (rblocks > 2048) rblocks = 2048;
        cqt_repack<<<rblocks, BLOCK, 0, stream>>>(kr, ki, wk, max_win, kpad);
        cqt_main<true><<<grid, block, lds_bytes, stream>>>(
            audio, wk, wk + (size_t)NBINS * kpad, out, T, nb, max_win, kpad, ngt, span);
    } else {
        cqt_main<false><<<grid, block, lds_bytes, stream>>>(
            audio, kr, ki, out, T, nb, max_win, max_win, ngt, span);
    }
}

// Round 3
// 131.683 us; speedup vs baseline: 3.0913x; 1.0055x over previous
//
#include <hip/hip_runtime.h>

#define HOP 512
#define NBINS 84
#define TT 8
#define BLOCK 256
#define KB 4        // bins per group (adjacent -> lengths within 19%)
#define NGROUPS 21  // NBINS / KB
#define CHUNK 256   // floats processed per inner iteration (64 lanes x float4)

// per-bin effective kernel length (nonzero prefix) + safety margin.
// Elements beyond the true ceil() are zeros in the kernel rows, so an
// over-estimate only adds exact zero FMAs.
__device__ __forceinline__ int bin_len(int k, int max_win) {
    double Q = 1.0 / (exp2(1.0 / 12.0) - 1.0);
    double freq = 32.7 * exp2((double)k / 12.0);
    int len = (int)ceil(Q * 22050.0 / freq) + 8;
    return len > max_win ? max_win : len;
}

// Repack kr/ki into ws with stride padded to a CHUNK multiple (zero-filled),
// so the main loop's vector reads never cross into the next row.
__global__ void cqt_repack(const float* __restrict__ kr, const float* __restrict__ ki,
                           float* __restrict__ dst, int max_win, int pad) {
    int total = 2 * NBINS * pad;
    for (int idx = blockIdx.x * blockDim.x + threadIdx.x; idx < total;
         idx += gridDim.x * blockDim.x) {
        int c = idx % pad;
        int row = idx / pad;  // 0..167
        int k = (row < NBINS) ? row : row - NBINS;
        const float* src = (row < NBINS) ? kr : ki;
        dst[idx] = (c < max_win) ? src[(size_t)k * max_win + c] : 0.0f;
    }
}

template <bool ALIGNED>
__global__ __launch_bounds__(BLOCK) void cqt_main(
    const float* __restrict__ audio,
    const float* __restrict__ krp, const float* __restrict__ kip,
    float* __restrict__ out,
    int T, int nb, int max_win, int kstride, int ngt, int span) {
    extern __shared__ float a_lds[];

    int b = blockIdx.x / ngt;
    int tg = blockIdx.x % ngt;
    int t0 = tg * TT;
    const float* ab = audio + (size_t)b * T;
    int g0 = t0 * HOP;

    // stage audio window (zero beyond T) into LDS
    for (int i = (int)threadIdx.x * 4; i < span; i += BLOCK * 4) {
        int g = g0 + i;
        float4 v;
        if (g + 3 < T) {
            v = *reinterpret_cast<const float4*>(ab + g);
        } else {
            v.x = (g     < T) ? ab[g]     : 0.0f;
            v.y = (g + 1 < T) ? ab[g + 1] : 0.0f;
            v.z = (g + 2 < T) ? ab[g + 2] : 0.0f;
            v.w = (g + 3 < T) ? ab[g + 3] : 0.0f;
        }
        *reinterpret_cast<float4*>(a_lds + i) = v;
    }
    __syncthreads();

    int wave = (int)threadIdx.x >> 6;
    int lane = (int)threadIdx.x & 63;

    // Greedy group->wave assignment by chunk count (uniform across threads).
    int l0 = 0, l1 = 0, l2 = 0, l3 = 0;
    for (int g = 0; g < NGROUPS; ++g) {
        int k0 = g * KB;
        int blen = bin_len(k0, max_win);  // longest bin in the group
        int chunks = (blen + CHUNK - 1) / CHUNK;

        int w = 0, lmin = l0;
        if (l1 < lmin) { lmin = l1; w = 1; }
        if (l2 < lmin) { lmin = l2; w = 2; }
        if (l3 < lmin) { lmin = l3; w = 3; }
        if (w == 0) l0 += chunks; else if (w == 1) l1 += chunks;
        else if (w == 2) l2 += chunks; else l3 += chunks;
        if (w != wave) continue;

        // ---- process group [k0, k0+3] ----
        const float* kr0 = krp + (size_t)k0 * kstride;
        const float* ki0 = kip + (size_t)k0 * kstride;

        float acc[64];  // idx = tb*8 + bin*2 + reim
#pragma unroll
        for (int i = 0; i < 64; ++i) acc[i] = 0.0f;

        for (int j = 0; j < chunks; ++j) {
            int n = j * CHUNK + lane * 4;
            float4 kr4[KB], ki4[KB];
#pragma unroll
            for (int i = 0; i < KB; ++i) {
                const float* rr = kr0 + (size_t)i * kstride;
                const float* mm = ki0 + (size_t)i * kstride;
                if (ALIGNED) {
                    kr4[i] = *reinterpret_cast<const float4*>(rr + n);
                    ki4[i] = *reinterpret_cast<const float4*>(mm + n);
                } else {
                    kr4[i].x = (n     < max_win) ? rr[n]     : 0.0f;
                    kr4[i].y = (n + 1 < max_win) ? rr[n + 1] : 0.0f;
                    kr4[i].z = (n + 2 < max_win) ? rr[n + 2] : 0.0f;
                    kr4[i].w = (n + 3 < max_win) ? rr[n + 3] : 0.0f;
                    ki4[i].x = (n     < max_win) ? mm[n]     : 0.0f;
                    ki4[i].y = (n + 1 < max_win) ? mm[n + 1] : 0.0f;
                    ki4[i].z = (n + 2 < max_win) ? mm[n + 2] : 0.0f;
                    ki4[i].w = (n + 3 < max_win) ? mm[n + 3] : 0.0f;
                }
            }
#pragma unroll
            for (int tb = 0; tb < TT; ++tb) {
                float4 a = *reinterpret_cast<const float4*>(a_lds + tb * HOP + n);
#pragma unroll
                for (int i = 0; i < KB; ++i) {
                    float r = acc[tb * 8 + i * 2 + 0];
                    float m = acc[tb * 8 + i * 2 + 1];
                    r = fmaf(a.x, kr4[i].x, r);
                    r = fmaf(a.y, kr4[i].y, r);
                    r = fmaf(a.z, kr4[i].z, r);
                    r = fmaf(a.w, kr4[i].w, r);
                    m = fmaf(a.x, ki4[i].x, m);
                    m = fmaf(a.y, ki4[i].y, m);
                    m = fmaf(a.z, ki4[i].z, m);
                    m = fmaf(a.w, ki4[i].w, m);
                    acc[tb * 8 + i * 2 + 0] = r;
                    acc[tb * 8 + i * 2 + 1] = m;
                }
            }
        }

        // Halving-butterfly reduction of 64 values across 64 lanes.
        // After 6 rounds, lane l holds the full sum of original acc[l].
#pragma unroll
        for (int r = 0; r < 6; ++r) {
            int off = 1 << r;
            int cnt = 32 >> r;
            bool hi = (lane & off) != 0;
#pragma unroll
            for (int i = 0; i < cnt; ++i) {
                float a = acc[2 * i], bb = acc[2 * i + 1];
                float mine = hi ? bb : a;
                float oth  = hi ? a : bb;
                mine += __shfl_xor(oth, off);
                acc[i] = mine;
            }
        }

        // lane l holds value l = tb*8 + bin*2 + reim
        int tb = lane >> 3;
        int bi = (lane >> 1) & 3;
        int rr = lane & 1;
        int t = t0 + tb;
        if (t < nb) {
            out[(((size_t)b * nb + t) * NBINS + (k0 + bi)) * 2 + rr] = acc[0];
        }
    }
}

extern "C" void kernel_launch(void* const* d_in, const int* in_sizes, int n_in,
                              void* d_out, int out_size, void* d_ws, size_t ws_size,
                              hipStream_t stream) {
    const float* audio = (const float*)d_in[0];
    const float* kr = (const float*)d_in[1];
    const float* ki = (const float*)d_in[2];
    float* out = (float*)d_out;

    const int T = 661500;                    // from setup_inputs
    const int B = in_sizes[0] / T;           // 4
    const int max_win = in_sizes[1] / NBINS; // 11341
    const int nb = T / HOP + 1;              // 1292

    // kernel-row stride padded to CHUNK multiple covering max_win+margin
    int kpad = ((max_win + 8 + CHUNK - 1) / CHUNK) * CHUNK;  // 11520
    int span = (TT - 1) * HOP + kpad;                        // 15104 floats
    size_t lds_bytes = (size_t)span * sizeof(float);         // ~60.4 KB

    int ngt = (nb + TT - 1) / TT;  // 162
    dim3 grid(B * ngt), block(BLOCK);

    size_t need = (size_t)2 * NBINS * kpad * sizeof(float);

    if (ws_size >= need) {
        float* wk = (float*)d_ws;
        int total = 2 * NBINS * kpad;
        int rblocks = (total + BLOCK - 1) / BLOCK;
        if (rblocks > 2048) rblocks = 2048;
        cqt_repack<<<rblocks, BLOCK, 0, stream>>>(kr, ki, wk, max_win, kpad);
        cqt_main<true><<<grid, block, lds_bytes, stream>>>(
            audio, wk, wk + (size_t)NBINS * kpad, out, T, nb, max_win, kpad, ngt, span);
    } else {
        cqt_main<false><<<grid, block, lds_bytes, stream>>>(
            audio, kr, ki, out, T, nb, max_win, max_win, ngt, span);
    }
}